// Round 20
// baseline (925.989 us; speedup 1.0000x reference)
//
#include <hip/hip_runtime.h>
#include <hip/hip_bf16.h>
#include <stdint.h>

#define NND 100000
#define KN 32
#define NE (NND*KN)
#define BB 2048
#define TT 50
#define DD0 64
#define HH 32
#define DD2 64
#define NROWS 34
#define BSH 9
#define NBUK ((NND + (1<<BSH) - 1) >> BSH)   // 196
#define PCHUNK 6250                           // NE / 512

typedef unsigned long long ull;

__device__ __forceinline__ void tf2x32(uint32_t k0, uint32_t k1, uint32_t& x0, uint32_t& x1){
  uint32_t k2 = k0 ^ k1 ^ 0x1BD11BDAu;
#define TFR(r) { x0 += x1; x1 = (x1<<(r)) | (x1>>(32-(r))); x1 ^= x0; }
  x0 += k0; x1 += k1;
  TFR(13) TFR(15) TFR(26) TFR(6)
  x0 += k1; x1 += k2 + 1u;
  TFR(17) TFR(29) TFR(16) TFR(24)
  x0 += k2; x1 += k0 + 2u;
  TFR(13) TFR(15) TFR(26) TFR(6)
  x0 += k0; x1 += k1 + 3u;
  TFR(17) TFR(29) TFR(16) TFR(24)
  x0 += k1; x1 += k2 + 4u;
  TFR(13) TFR(15) TFR(26) TFR(6)
  x0 += k2; x1 += k0 + 5u;
#undef TFR
}

__device__ __forceinline__ uint32_t xorbits(uint32_t ka, uint32_t kb, uint32_t i){
  uint32_t x0=0u, x1=i;
  tf2x32(ka,kb,x0,x1);
  return x0^x1;
}

__global__ void keys_kernel(uint32_t* keys, int* bcnt){
  int t=threadIdx.x;
  for(int i=t;i<NBUK+1;i+=64) bcnt[i]=0;
  if(t==0 && blockIdx.x==0){
    for(int cid=0;cid<4;++cid){
      uint32_t K0=0u,K1=(uint32_t)cid;
      tf2x32(0u,42u,K0,K1);
      uint32_t a0=0u,a1=0u; tf2x32(K0,K1,a0,a1);
      uint32_t b0=0u,b1=1u; tf2x32(K0,K1,b0,b1);
      keys[cid*4+0]=a0; keys[cid*4+1]=a1;
      keys[cid*4+2]=b0; keys[cid*4+3]=b1;
    }
    for(int r=0;r<2;++r){
      uint32_t F0=0u,F1=(uint32_t)(2*r);
      tf2x32(0u,7u,F0,F1);
      uint32_t a0=0u,a1=0u; tf2x32(F0,F1,a0,a1);
      uint32_t b0=0u,b1=1u; tf2x32(F0,F1,b0,b1);
      keys[16+r*4+0]=a0; keys[16+r*4+1]=a1;
      keys[16+r*4+2]=b0; keys[16+r*4+3]=b1;
    }
  }
}

// ===== bucketed CSR build =====
__global__ void __launch_bounds__(256) bcount_kernel(const int* __restrict__ edge, int* bcnt){
  __shared__ int h[NBUK];
  int t=threadIdx.x;
  for(int i=t;i<NBUK;i+=256) h[i]=0;
  __syncthreads();
  int start=blockIdx.x*PCHUNK, end=start+PCHUNK;
  for(int e=start+t;e<end;e+=256) atomicAdd(&h[edge[e]>>BSH],1);
  __syncthreads();
  for(int i=t;i<NBUK;i+=256) if(h[i]) atomicAdd(&bcnt[i],h[i]);
}

__global__ void bscan_kernel(const int* bcnt, int* boff, int* bcur, int* off){
  if(threadIdx.x==0 && blockIdx.x==0){
    int run=0;
    for(int i=0;i<NBUK;++i){ boff[i]=run; bcur[i]=run; run+=bcnt[i]; }
    boff[NBUK]=run;
    off[NND]=NE;
  }
}

__global__ void __launch_bounds__(256) bscatter_kernel(const int* __restrict__ edge,
    int* bcur, ull* __restrict__ tmp8){
  __shared__ int h[NBUK], base[NBUK], lcur[NBUK];
  int t=threadIdx.x;
  for(int i=t;i<NBUK;i+=256){ h[i]=0; lcur[i]=0; }
  __syncthreads();
  int start=blockIdx.x*PCHUNK, end=start+PCHUNK;
  for(int e=start+t;e<end;e+=256) atomicAdd(&h[edge[e]>>BSH],1);
  __syncthreads();
  for(int i=t;i<NBUK;i+=256) base[i] = h[i]? atomicAdd(&bcur[i],h[i]) : 0;
  __syncthreads();
  for(int e=start+t;e<end;e+=256){
    int d=edge[e];
    int b=d>>BSH;
    int r=atomicAdd(&lcur[b],1);
    tmp8[base[b]+r] = (((ull)(unsigned)d)<<32) | (unsigned)e;
  }
}

__global__ void __launch_bounds__(256) bucket_csr_kernel(const int* __restrict__ boff,
    const ull* __restrict__ tmp8, int* __restrict__ off, float* __restrict__ inv,
    int* __restrict__ col){
  __shared__ int cnt[512], pref[512], cur2[512];
  int b=blockIdx.x, t=threadIdx.x;
  int nb=b<<BSH;
  for(int i=t;i<512;i+=256) cnt[i]=0;
  __syncthreads();
  int lo=boff[b], hi=boff[b+1];
  for(int i=lo+t;i<hi;i+=256){
    int ld=(int)(tmp8[i]>>32)-nb;
    atomicAdd(&cnt[ld],1);
  }
  __syncthreads();
  if(t==0){ int run=lo; for(int i=0;i<512;++i){ pref[i]=run; cur2[i]=run; run+=cnt[i]; } }
  __syncthreads();
  for(int i=t;i<512;i+=256){
    int d=nb+i;
    if(d<NND){ off[d]=pref[i]; int c=cnt[i]; inv[d]=1.0f/(float)(c>0?c:1); }
  }
  __syncthreads();
  for(int i=lo+t;i<hi;i+=256){
    ull v=tmp8[i];
    int ld=(int)(v>>32)-nb;
    int r=atomicAdd(&cur2[ld],1);
    col[r]=(int)(v&0xffffffffu);
  }
}

// ===== fallback build =====
__global__ void count_kernel(const int* dst, int* cnt){
  int e = blockIdx.x*256 + threadIdx.x;
  if(e < NE) atomicAdd(&cnt[dst[e]], 1);
}
__global__ void scan_kernel(const int* cnt, int* off, int* cur, float* inv){
  __shared__ int part[1024];
  int t = threadIdx.x;
  const int CH = (NND + 1023)/1024;
  int lo = t*CH, hi = lo+CH; if(hi>NND) hi=NND;
  int s=0;
  for(int i=lo;i<hi;++i) s += cnt[i];
  part[t]=s;
  __syncthreads();
  if(t==0){ int run=0; for(int i=0;i<1024;++i){ int v=part[i]; part[i]=run; run+=v; } }
  __syncthreads();
  int run = part[t];
  for(int i=lo;i<hi;++i){
    off[i]=run; cur[i]=run;
    int c=cnt[i];
    inv[i]=1.0f/(float)(c>0?c:1);
    run+=c;
  }
  if(t==0) off[NND]=NE;
}
__global__ void fill_kernel(const int* dst, int* cur, int* col){
  int e = blockIdx.x*256 + threadIdx.x;
  if(e < NE){
    int d = dst[e];
    int slot = atomicAdd(&cur[d],1);
    col[slot] = e;
  }
}

// wave odd-even sort of each CSR segment
__global__ void __launch_bounds__(256) sortseg_wave_kernel(const int* off, int* col){
  int t=threadIdx.x, lane=t&63, w=t>>6;
  int node = blockIdx.x*4 + w;
  if(node>=NND) return;
  int lo=off[node], hi=off[node+1];
  int deg=hi-lo;
  if(deg<=1) return;
  if(deg<=64){
    int v = (lane<deg)? col[lo+lane] : 0x7fffffff;
    for(int p=0;p<64;++p){
      int partner;
      if((p&1)==0) partner = lane^1;
      else partner = (lane==0||lane==63)? lane : ((lane&1)? lane+1 : lane-1);
      int pv = __shfl(v, partner, 64);
      if(partner>lane) v = v<pv? v:pv;
      else if(partner<lane) v = v>pv? v:pv;
    }
    if(lane<deg) col[lo+lane]=v;
  } else if(lane==0){
    for(int i=lo+1;i<hi;++i){
      int v=col[i]; int j=i-1;
      while(j>=lo && col[j]>v){ col[j+1]=col[j]; --j; }
      col[j+1]=v;
    }
  }
}

// edge-id -> source-node (e>>5), post-sort; removes a shift from every gather
__global__ void srcify_kernel(int* col){
  int i = blockIdx.x*256 + threadIdx.x;
  if(i < NE) col[i] >>= 5;
}

// order-preserving 16-deep batched gather, 64-wide (col holds src node)
__device__ __forceinline__ float gather_seq(const float* __restrict__ src, int S, int d,
    const int* __restrict__ col, int lo, int hi, int lane){
  float acc=0.f;
  int deg=hi-lo, base=0;
  while(base<deg){
    int rem=deg-base; int cw = rem<64?rem:64;
    int cv = col[lo+base+ (lane<cw?lane:cw-1)];
    for(int k=0;k<cw;k+=16){
      int m=cw-k;
      float v[16];
#pragma unroll
      for(int j=0;j<16;++j){
        int q = (j<m)? k+j : k;
        int s = __shfl(cv,q,64);
        v[j] = src[(size_t)s*S+d];
      }
#pragma unroll
      for(int j=0;j<16;++j) if(j<m) acc += v[j];
    }
    base+=cw;
  }
  return acc;
}

// same, 32-wide (half-wave)
__device__ __forceinline__ float gather_seq32(const float* __restrict__ src, int S, int d,
    const int* __restrict__ col, int lo, int hi, int l){
  float acc=0.f;
  int deg=hi-lo, base=0;
  while(base<deg){
    int rem=deg-base; int cw = rem<32?rem:32;
    int cv = col[lo+base+ (l<cw?l:cw-1)];
    for(int k=0;k<cw;k+=16){
      int m=cw-k;
      float v[16];
#pragma unroll
      for(int j=0;j<16;++j){
        int q = (j<m)? k+j : k;
        int s = __shfl(cv,q,32);
        v[j] = src[(size_t)s*S+d];
      }
#pragma unroll
      for(int j=0;j<16;++j) if(j<m) acc += v[j];
    }
    base+=cw;
  }
  return acc;
}

// h1base = leaky_relu(agg@Wl1.T + bl1 + x@Wr1.T); 512 threads, 8 nodes/block
__global__ void __launch_bounds__(512) sage1base_kernel(const float* __restrict__ x,
    const int* __restrict__ off, const int* __restrict__ col,
    const float* __restrict__ inv, const float* __restrict__ Wl,
    const float* __restrict__ bl, const float* __restrict__ Wr,
    float* __restrict__ h1base){
  __shared__ float sWlT[DD0*HH], sWrT[DD0*HH];
  __shared__ float sA[8][DD0], sX[8][DD0];
  int t=threadIdx.x, lane=t&63, w=t>>6;
  for(int j=t;j<HH*DD0;j+=512){
    int k=j>>5, h=j&31;
    sWlT[j]=Wl[h*DD0+k]; sWrT[j]=Wr[h*DD0+k];
  }
  int node=blockIdx.x*8+w;
  int lo=off[node], hi=off[node+1];
  float acc=gather_seq(x,DD0,lane,col,lo,hi,lane);
  acc *= inv[node];
  sA[w][lane]=acc;
  sX[w][lane]=x[(size_t)node*DD0+lane];
  __syncthreads();
  if(lane<HH){
    float s1=0.f, s2=0.f;
    for(int k=0;k<DD0;++k){
      s1 += sA[w][k]*sWlT[k*HH+lane];
      s2 += sX[w][k]*sWrT[k*HH+lane];
    }
    float v=s1+bl[lane]+s2;
    v = (v>=0.f) ? v : 0.01f*v;
    h1base[(size_t)node*HH+lane]=v;
  }
}

__global__ void __launch_bounds__(256) mask_kernel(const float* __restrict__ h1base,
    const uint32_t* __restrict__ keys, int cid, float* __restrict__ h1){
  int j = blockIdx.x*256 + threadIdx.x;
  if(j < NND*HH){
    uint32_t bits = xorbits(keys[cid*4+0],keys[cid*4+1],(uint32_t)j);
    float v = h1base[j];
    h1[j] = ((bits>>31)==0u) ? 2.f*v : 0.f;
  }
}

// full sage1 (fallback tiers)
__global__ void __launch_bounds__(256) sage1_kernel(const float* __restrict__ x,
    const int* __restrict__ off, const int* __restrict__ col,
    const float* __restrict__ inv, const float* __restrict__ Wl,
    const float* __restrict__ bl, const float* __restrict__ Wr,
    const uint32_t* __restrict__ keys, int cid, float* __restrict__ h1o){
  __shared__ float sWlT[DD0*HH], sWrT[DD0*HH];
  __shared__ float sA[4][DD0], sX[4][DD0];
  int t=threadIdx.x, lane=t&63, w=t>>6;
  for(int j=t;j<HH*DD0;j+=256){
    int k=j>>5, h=j&31;
    sWlT[j]=Wl[h*DD0+k]; sWrT[j]=Wr[h*DD0+k];
  }
  int node=blockIdx.x*4+w;
  int lo=off[node], hi=off[node+1];
  float acc=gather_seq(x,DD0,lane,col,lo,hi,lane);
  acc *= inv[node];
  sA[w][lane]=acc;
  sX[w][lane]=x[(size_t)node*DD0+lane];
  __syncthreads();
  if(lane<HH){
    float s1=0.f, s2=0.f;
    for(int k=0;k<DD0;++k){
      s1 += sA[w][k]*sWlT[k*HH+lane];
      s2 += sX[w][k]*sWrT[k*HH+lane];
    }
    float v=s1+bl[lane]+s2;
    v = (v>=0.f) ? v : 0.01f*v;
    uint32_t j=(uint32_t)(node*HH+lane);
    uint32_t bits = xorbits(keys[cid*4+0],keys[cid*4+1],j);
    v = ((bits>>31)==0u) ? 2.f*v : 0.f;
    h1o[(size_t)node*HH+lane]=v;
  }
}

__device__ __forceinline__ float g_row_core(int n, int lane,
    const float* __restrict__ h1, const int* __restrict__ off,
    const int* __restrict__ col, const float* __restrict__ inv,
    const float* __restrict__ sWlT, const float* __restrict__ sWrT,
    const float* __restrict__ bl2, uint32_t k2a, uint32_t k2b){
  int lo=off[n], hi=off[n+1];
  int d=lane&31;
  float acc=gather_seq(h1,HH,d,col,lo,hi,lane);
  float aggd = acc*inv[n];
  float hd   = h1[(size_t)n*HH+d];
  float s1=0.f, s2=0.f;
  for(int k=0;k<HH;++k){
    float ak=__shfl(aggd,k,64);
    float hk=__shfl(hd,k,64);
    s1 += ak*sWlT[k*DD2+lane];
    s2 += hk*sWrT[k*DD2+lane];
  }
  float v=s1+bl2[lane]+s2;
  uint32_t j=(uint32_t)n*64u+(uint32_t)lane;
  uint32_t bits = xorbits(k2a,k2b,j);
  v = ((bits>>31)==0u) ? 2.f*v : 0.f;
  float ss=v*v;
  for(int m=1;m<64;m<<=1) ss += __shfl_xor(ss,m,64);
  return v/fmaxf(sqrtf(ss),1e-12f);
}

// half-wave g-row body (both output dims l, l+32); returns via pointers
__device__ __forceinline__ void g_row_half(int node, int l,
    const float* __restrict__ h1, const int* __restrict__ off,
    const int* __restrict__ col, const float* __restrict__ inv,
    const float* __restrict__ sWlT, const float* __restrict__ sWrT,
    const float* __restrict__ bl2, uint32_t k2a, uint32_t k2b,
    float* oa, float* ob){
  int lo=off[node], hi=off[node+1];
  float acc = gather_seq32(h1,HH,l,col,lo,hi,l);
  float aggd = acc*inv[node];
  float hd   = h1[(size_t)node*HH+l];
  float s1a=0.f,s2a=0.f,s1b=0.f,s2b=0.f;
  for(int k=0;k<HH;++k){
    float ak=__shfl(aggd,k,32);
    float hk=__shfl(hd,k,32);
    s1a += ak*sWlT[k*DD2+l];      s2a += hk*sWrT[k*DD2+l];
    s1b += ak*sWlT[k*DD2+l+32];   s2b += hk*sWrT[k*DD2+l+32];
  }
  float va=s1a+bl2[l]+s2a;
  float vb=s1b+bl2[l+32]+s2b;
  uint32_t ja=(uint32_t)node*64u+(uint32_t)l;
  va = ((xorbits(k2a,k2b,ja)>>31)==0u)     ? 2.f*va : 0.f;
  vb = ((xorbits(k2a,k2b,ja+32u)>>31)==0u) ? 2.f*vb : 0.f;
  float ssa=va*va, ssb=vb*vb;
  for(int m=1;m<32;m<<=1){ ssa += __shfl_xor(ssa,m,32); ssb += __shfl_xor(ssb,m,32); }
  float nr=fmaxf(sqrtf(ssa+ssb),1e-12f);
  *oa = va/nr; *ob = vb/nr;
}

// TWO g-rows per wave into rowbuf (tier-2 path)
__global__ void __launch_bounds__(512) grows2_kernel(
    const float* __restrict__ h1, const int* __restrict__ off,
    const int* __restrict__ col, const float* __restrict__ inv,
    const float* __restrict__ Wl2, const float* __restrict__ bl2,
    const float* __restrict__ Wr2, const uint32_t* __restrict__ keys, int cid,
    const int* __restrict__ users, const int* __restrict__ pid_arr,
    const int* __restrict__ adj, float* __restrict__ rowbuf){
  __shared__ float sWlT[HH*DD2], sWrT[HH*DD2];
  int t=threadIdx.x, lane=t&63, w=t>>6;
  int half=lane>>5, l=lane&31;
  for(int j=t;j<HH*DD2;j+=512){
    int k=j>>6, d=j&63;
    sWlT[j]=Wl2[d*HH+k]; sWrT[j]=Wr2[d*HH+k];
  }
  __syncthreads();
  int wg = blockIdx.x*16 + w*2 + half;
  int b = wg/NROWS, r = wg - b*NROWS;
  int pid = pid_arr[b];
  int node = (r==0)? users[b] : ((r==1)? pid : adj[(size_t)pid*KN + (r-2)]);
  float va,vb;
  g_row_half(node,l,h1,off,col,inv,sWlT,sWrT,bl2,keys[cid*4+2],keys[cid*4+3],&va,&vb);
  rowbuf[(size_t)wg*DD2 + l]      = va;
  rowbuf[(size_t)wg*DD2 + l + 32] = vb;
}

// ===== tier-3 dedup path =====
__global__ void __launch_bounds__(256) mark_kernel(const int* __restrict__ users,
    const int* __restrict__ pid_arr, const int* __restrict__ adj,
    int* __restrict__ flags, int gen){
  int i = blockIdx.x*256 + threadIdx.x;       // i in [0, BB*NROWS)
  if(i >= BB*NROWS) return;
  int b = i/NROWS, r = i - b*NROWS;
  int pid = pid_arr[b];
  int node = (r==0)? users[b] : ((r==1)? pid : adj[(size_t)pid*KN + (r-2)]);
  flags[node] = gen;                          // benign same-value races
}

// one g-row per flagged node -> gtab[node]; 2 nodes/wave via half-waves
__global__ void __launch_bounds__(512) grows_dedup_kernel(
    const float* __restrict__ h1, const int* __restrict__ off,
    const int* __restrict__ col, const float* __restrict__ inv,
    const float* __restrict__ Wl2, const float* __restrict__ bl2,
    const float* __restrict__ Wr2, const uint32_t* __restrict__ keys, int cid,
    const int* __restrict__ flags, int gen, float* __restrict__ gtab){
  __shared__ float sWlT[HH*DD2], sWrT[HH*DD2];
  int t=threadIdx.x, lane=t&63, w=t>>6;
  int half=lane>>5, l=lane&31;
  for(int j=t;j<HH*DD2;j+=512){
    int k=j>>6, d=j&63;
    sWlT[j]=Wl2[d*HH+k]; sWrT[j]=Wr2[d*HH+k];
  }
  __syncthreads();
  int node = blockIdx.x*16 + w*2 + half;      // grid*16 >= NND
  if(node >= NND) return;
  if(flags[node] != gen) return;
  float va,vb;
  g_row_half(node,l,h1,off,col,inv,sWlT,sWrT,bl2,keys[cid*4+2],keys[cid*4+3],&va,&vb);
  gtab[(size_t)node*DD2 + l]      = va;
  gtab[(size_t)node*DD2 + l + 32] = vb;
}

// sel kernels reading gtab via node indirection (tier-3)
__global__ void __launch_bounds__(64) sel1d_kernel(
    const float* __restrict__ gtab,
    const int* __restrict__ users, const int* __restrict__ pid_arr,
    const int* __restrict__ adj, int* __restrict__ oh_out, float* __restrict__ l1_out){
  int b=blockIdx.x, t=threadIdx.x;
  __shared__ float wsh[DD2];
  __shared__ float ps[KN];
  int u=users[b], pid=pid_arr[b];
  wsh[t] = gtab[(size_t)u*DD2+t]*gtab[(size_t)pid*DD2+t];
  __syncthreads();
  if(t<KN){
    int nb2=adj[(size_t)pid*KN+t];
    float p=0.f;
    const float* rr = gtab + (size_t)nb2*DD2;
    for(int d=0;d<DD2;++d) p += rr[d]*wsh[d];
    ps[t]=p;
  }
  __syncthreads();
  if(t==0){
    float m=ps[0]; for(int k=1;k<KN;++k) m=fmaxf(m,ps[k]);
    float s=0.f;  for(int k=0;k<KN;++k) s += expf(ps[k]-m);
    int best=0; float bv=ps[0];
    for(int k=1;k<KN;++k) if(ps[k]>bv){bv=ps[k];best=k;}
    oh_out[b]=adj[(size_t)pid*KN+best];
    l1_out[b]=(ps[best]-m)-logf(s);
  }
}

__global__ void __launch_bounds__(64) sel2d_kernel(
    const float* __restrict__ gtab, const uint32_t* __restrict__ keys, int kf_idx,
    const int* __restrict__ users, const int* __restrict__ oh,
    const int* __restrict__ adj,
    const float* __restrict__ du, const float* __restrict__ di,
    const int* __restrict__ train, const int* __restrict__ neg,
    const float* __restrict__ l1, int round,
    int* __restrict__ gneg_out, float* __restrict__ out){
  int b=blockIdx.x, t=threadIdx.x;
  __shared__ float wsh[DD2];
  __shared__ float ps[KN], lps[KN], rk[KN];
  __shared__ int nid[KN], cand[KN];
  __shared__ float msh[2];
  int u=users[b], pid=oh[b];
  wsh[t] = gtab[(size_t)u*DD2+t]*gtab[(size_t)pid*DD2+t];
  __syncthreads();
  if(t<KN){
    int nb2=adj[(size_t)pid*KN+t];
    float p=0.f;
    const float* rr = gtab + (size_t)nb2*DD2;
    for(int d=0;d<DD2;++d) p += rr[d]*wsh[d];
    ps[t]=p;
  }
  __syncthreads();
  if(t==0){
    float m=ps[0]; for(int k=1;k<KN;++k) m=fmaxf(m,ps[k]);
    float s=0.f;  for(int k=0;k<KN;++k) s += expf(ps[k]-m);
    msh[0]=m; msh[1]=logf(s);
    for(int k=0;k<KN;++k) nid[k]=k;
    for(int i=1;i<KN;++i){
      int v=nid[i]; float pv=ps[v]; int j=i-1;
      while(j>=0 && ps[nid[j]]>pv){ nid[j+1]=nid[j]; --j; }
      nid[j+1]=v;
    }
  }
  __syncthreads();
  if(t<KN){
    int n=t, c=adj[(size_t)pid*KN + nid[n]];
    if(c<0 || c>49999){
      uint32_t i0=(uint32_t)(b*KN+n);
      const uint32_t* fk = keys + 16 + kf_idx*4;
      uint32_t hb = xorbits(fk[0], fk[1], i0);
      uint32_t lb = xorbits(fk[2], fk[3], i0);
      c=(int)(((hb%50000u)*17296u + (lb%50000u))%50000u);
    }
    cand[n]=c;
    lps[n]=(ps[nid[n]]-msh[0])-msh[1];
    float rr=0.f;
    for(int d=0;d<DD2;++d) rr += du[(size_t)u*DD2+d]*di[(size_t)c*DD2+d];
    rk[n]=rr;
  }
  __syncthreads();
  if(t==0){
    int best=0; float bv=rk[0];
    for(int n=1;n<KN;++n) if(rk[n]>bv){bv=rk[n];best=n;}
    int gn=cand[best]; float lsel=lps[best];
    bool it=false;
    for(int t2=0;t2<TT;++t2) if(train[(size_t)b*TT+t2]==gn){it=true;break;}
    if(it) gn=neg[b];
    gneg_out[b]=gn;
    out[b*2+round]        = (float)gn;
    out[BB*2 + b*2+round] = l1[b]+lsel;
  }
}

// tier-2 sel kernels (rowbuf-based)
__global__ void __launch_bounds__(64) sel1_kernel(
    const float* __restrict__ rowbuf,
    const int* __restrict__ users, const int* __restrict__ pid_arr,
    const int* __restrict__ adj, int* __restrict__ oh_out, float* __restrict__ l1_out){
  int b=blockIdx.x, t=threadIdx.x;
  __shared__ float wsh[DD2];
  __shared__ float ps[KN];
  const float* rb = rowbuf + (size_t)b*NROWS*DD2;
  wsh[t] = rb[t]*rb[DD2+t];
  __syncthreads();
  if(t<KN){
    float p=0.f;
    const float* rr = rb + (size_t)(2+t)*DD2;
    for(int d=0;d<DD2;++d) p += rr[d]*wsh[d];
    ps[t]=p;
  }
  __syncthreads();
  if(t==0){
    float m=ps[0]; for(int k=1;k<KN;++k) m=fmaxf(m,ps[k]);
    float s=0.f;  for(int k=0;k<KN;++k) s += expf(ps[k]-m);
    int best=0; float bv=ps[0];
    for(int k=1;k<KN;++k) if(ps[k]>bv){bv=ps[k];best=k;}
    oh_out[b]=adj[(size_t)pid_arr[b]*KN+best];
    l1_out[b]=(ps[best]-m)-logf(s);
  }
}

__global__ void __launch_bounds__(64) sel2_kernel(
    const float* __restrict__ rowbuf, const uint32_t* __restrict__ keys, int kf_idx,
    const int* __restrict__ users, const int* __restrict__ oh,
    const int* __restrict__ adj,
    const float* __restrict__ du, const float* __restrict__ di,
    const int* __restrict__ train, const int* __restrict__ neg,
    const float* __restrict__ l1, int round,
    int* __restrict__ gneg_out, float* __restrict__ out){
  int b=blockIdx.x, t=threadIdx.x;
  __shared__ float wsh[DD2];
  __shared__ float ps[KN], lps[KN], rk[KN];
  __shared__ int nid[KN], cand[KN];
  __shared__ float msh[2];
  const float* rb = rowbuf + (size_t)b*NROWS*DD2;
  wsh[t] = rb[t]*rb[DD2+t];
  __syncthreads();
  if(t<KN){
    float p=0.f;
    const float* rr = rb + (size_t)(2+t)*DD2;
    for(int d=0;d<DD2;++d) p += rr[d]*wsh[d];
    ps[t]=p;
  }
  __syncthreads();
  if(t==0){
    float m=ps[0]; for(int k=1;k<KN;++k) m=fmaxf(m,ps[k]);
    float s=0.f;  for(int k=0;k<KN;++k) s += expf(ps[k]-m);
    msh[0]=m; msh[1]=logf(s);
    for(int k=0;k<KN;++k) nid[k]=k;
    for(int i=1;i<KN;++i){
      int v=nid[i]; float pv=ps[v]; int j=i-1;
      while(j>=0 && ps[nid[j]]>pv){ nid[j+1]=nid[j]; --j; }
      nid[j+1]=v;
    }
  }
  __syncthreads();
  if(t<KN){
    int n=t, c=adj[(size_t)oh[b]*KN + nid[n]];
    if(c<0 || c>49999){
      uint32_t i0=(uint32_t)(b*KN+n);
      const uint32_t* fk = keys + 16 + kf_idx*4;
      uint32_t hb = xorbits(fk[0], fk[1], i0);
      uint32_t lb = xorbits(fk[2], fk[3], i0);
      c=(int)(((hb%50000u)*17296u + (lb%50000u))%50000u);
    }
    cand[n]=c;
    lps[n]=(ps[nid[n]]-msh[0])-msh[1];
    int u=users[b];
    float rr=0.f;
    for(int d=0;d<DD2;++d) rr += du[(size_t)u*DD2+d]*di[(size_t)c*DD2+d];
    rk[n]=rr;
  }
  __syncthreads();
  if(t==0){
    int best=0; float bv=rk[0];
    for(int n=1;n<KN;++n) if(rk[n]>bv){bv=rk[n];best=n;}
    int gn=cand[best]; float lsel=lps[best];
    bool it=false;
    for(int t2=0;t2<TT;++t2) if(train[(size_t)b*TT+t2]==gn){it=true;break;}
    if(it) gn=neg[b];
    gneg_out[b]=gn;
    out[b*2+round]        = (float)gn;
    out[BB*2 + b*2+round] = l1[b]+lsel;
  }
}

// ===== fallback fused steps (tier 0) =====
__global__ void __launch_bounds__(256) fstep1_kernel(
    const float* __restrict__ h1, const int* __restrict__ off,
    const int* __restrict__ col, const float* __restrict__ inv,
    const float* __restrict__ Wl2, const float* __restrict__ bl2,
    const float* __restrict__ Wr2, const uint32_t* __restrict__ keys, int cid,
    const int* __restrict__ users, const int* __restrict__ pid_arr,
    const int* __restrict__ adj, int* __restrict__ oh_out, float* __restrict__ l1_out){
  __shared__ float sWlT[HH*DD2], sWrT[HH*DD2];
  __shared__ float rows[2+KN][DD2+1];
  __shared__ int nds[2+KN];
  __shared__ float ps[KN];
  int t=threadIdx.x, lane=t&63, w=t>>6, b=blockIdx.x;
  for(int j=t;j<HH*DD2;j+=256){
    int k=j>>6, d=j&63;
    sWlT[j]=Wl2[d*HH+k]; sWrT[j]=Wr2[d*HH+k];
  }
  if(t==0){ nds[0]=users[b]; nds[1]=pid_arr[b]; }
  if(t>=2 && t<2+KN) nds[t]=adj[(size_t)pid_arr[b]*KN + (t-2)];
  __syncthreads();
  uint32_t k2a=keys[cid*4+2], k2b=keys[cid*4+3];
  for(int r=w; r<2+KN; r+=4)
    rows[r][lane]=g_row_core(nds[r],lane,h1,off,col,inv,sWlT,sWrT,bl2,k2a,k2b);
  __syncthreads();
  if(t<KN){
    float p=0.f;
    for(int d=0;d<DD2;++d) p += rows[2+t][d]*(rows[0][d]*rows[1][d]);
    ps[t]=p;
  }
  __syncthreads();
  if(t==0){
    float m=ps[0]; for(int k=1;k<KN;++k) m=fmaxf(m,ps[k]);
    float s=0.f;  for(int k=0;k<KN;++k) s += expf(ps[k]-m);
    int best=0; float bv=ps[0];
    for(int k=1;k<KN;++k) if(ps[k]>bv){bv=ps[k];best=k;}
    oh_out[b]=nds[2+best];
    l1_out[b]=(ps[best]-m)-logf(s);
  }
}

__global__ void __launch_bounds__(256) fstep2_kernel(
    const float* __restrict__ h1, const int* __restrict__ off,
    const int* __restrict__ col, const float* __restrict__ inv,
    const float* __restrict__ Wl2, const float* __restrict__ bl2,
    const float* __restrict__ Wr2, const uint32_t* __restrict__ keys,
    int cid, int kf_idx,
    const int* __restrict__ users, const int* __restrict__ oh,
    const int* __restrict__ adj,
    const float* __restrict__ du, const float* __restrict__ di,
    const int* __restrict__ train, const int* __restrict__ neg,
    const float* __restrict__ l1, int round,
    int* __restrict__ gneg_out, float* __restrict__ out){
  __shared__ float sWlT[HH*DD2], sWrT[HH*DD2];
  __shared__ float rows[2+KN][DD2+1];
  __shared__ int nds[2+KN];
  __shared__ float ps[KN], lps[KN], rk[KN];
  __shared__ int nid[KN], cand[KN];
  __shared__ float msh[2];
  int t=threadIdx.x, lane=t&63, w=t>>6, b=blockIdx.x;
  for(int j=t;j<HH*DD2;j+=256){
    int k=j>>6, d=j&63;
    sWlT[j]=Wl2[d*HH+k]; sWrT[j]=Wr2[d*HH+k];
  }
  if(t==0){ nds[0]=users[b]; nds[1]=oh[b]; }
  if(t>=2 && t<2+KN) nds[t]=adj[(size_t)oh[b]*KN + (t-2)];
  __syncthreads();
  uint32_t k2a=keys[cid*4+2], k2b=keys[cid*4+3];
  for(int r=w; r<2+KN; r+=4)
    rows[r][lane]=g_row_core(nds[r],lane,h1,off,col,inv,sWlT,sWrT,bl2,k2a,k2b);
  __syncthreads();
  if(t<KN){
    float p=0.f;
    for(int d=0;d<DD2;++d) p += rows[2+t][d]*(rows[0][d]*rows[1][d]);
    ps[t]=p;
  }
  __syncthreads();
  if(t==0){
    float m=ps[0]; for(int k=1;k<KN;++k) m=fmaxf(m,ps[k]);
    float s=0.f;  for(int k=0;k<KN;++k) s += expf(ps[k]-m);
    msh[0]=m; msh[1]=logf(s);
    for(int k=0;k<KN;++k) nid[k]=k;
    for(int i=1;i<KN;++i){
      int v=nid[i]; float pv=ps[v]; int j=i-1;
      while(j>=0 && ps[nid[j]]>pv){ nid[j+1]=nid[j]; --j; }
      nid[j+1]=v;
    }
  }
  __syncthreads();
  if(t<KN){
    int n=t, c=nds[2+nid[n]];
    if(c<0 || c>49999){
      uint32_t i0=(uint32_t)(b*KN+n);
      const uint32_t* fk = keys + 16 + kf_idx*4;
      uint32_t hb = xorbits(fk[0], fk[1], i0);
      uint32_t lb = xorbits(fk[2], fk[3], i0);
      c=(int)(((hb%50000u)*17296u + (lb%50000u))%50000u);
    }
    cand[n]=c;
    lps[n]=(ps[nid[n]]-msh[0])-msh[1];
    int u=nds[0];
    float rr=0.f;
    for(int d=0;d<DD2;++d) rr += du[(size_t)u*DD2+d]*di[(size_t)c*DD2+d];
    rk[n]=rr;
  }
  __syncthreads();
  if(t==0){
    int best=0; float bv=rk[0];
    for(int n=1;n<KN;++n) if(rk[n]>bv){bv=rk[n];best=n;}
    int gn=cand[best]; float lsel=lps[best];
    bool it=false;
    for(int t2=0;t2<TT;++t2) if(train[(size_t)b*TT+t2]==gn){it=true;break;}
    if(it) gn=neg[b];
    gneg_out[b]=gn;
    out[b*2+round]        = (float)gn;
    out[BB*2 + b*2+round] = l1[b]+lsel;
  }
}

extern "C" void kernel_launch(void* const* d_in, const int* in_sizes, int n_in,
                              void* d_out, int out_size, void* d_ws, size_t ws_size,
                              hipStream_t stream) {
  const int*   users=(const int*)d_in[0];
  const int*   pos  =(const int*)d_in[1];
  const int*   neg  =(const int*)d_in[2];
  const int*   train=(const int*)d_in[3];
  const int*   adj  =(const int*)d_in[4];
  const int*   edge =(const int*)d_in[5];
  const float* ent  =(const float*)d_in[6];
  const float* Wl1  =(const float*)d_in[7];
  const float* bl1  =(const float*)d_in[8];
  const float* Wr1  =(const float*)d_in[9];
  const float* Wl2  =(const float*)d_in[10];
  const float* bl2  =(const float*)d_in[11];
  const float* Wr2  =(const float*)d_in[12];
  const float* du   =(const float*)d_in[13];
  const float* di   =(const float*)d_in[14];
  float* out=(float*)d_out;

  char* wsb=(char*)d_ws;
  size_t o=0;
  auto alloc=[&](size_t n)->char*{ char* p=wsb+o; o=(o+n+255)&~(size_t)255; return p; };
  uint32_t* keys=(uint32_t*)alloc(32*4);
  int*   bcnt=(int*)alloc((size_t)(NBUK+1)*4);
  int*   boff=(int*)alloc((size_t)(NBUK+1)*4);
  int*   bcur=(int*)alloc((size_t)NBUK*4);
  int*   ohb=(int*)alloc((size_t)BB*4);
  float* l1b=(float*)alloc((size_t)BB*4);
  int*   g1b=(int*)alloc((size_t)BB*4);
  int*   g2b=(int*)alloc((size_t)BB*4);
  int*   cnt=(int*)alloc((size_t)NND*4);
  int*   off=(int*)alloc((size_t)(NND+1)*4);
  int*   cur=(int*)alloc((size_t)NND*4);
  float* inv=(float*)alloc((size_t)NND*4);
  int*   col=(int*)alloc((size_t)NE*4);
  float* h1 =(float*)alloc((size_t)NND*HH*4);
  float* rowbuf=(float*)alloc((size_t)BB*NROWS*DD2*4);
  size_t o_rowbuf = o;
  float* h1base=(float*)alloc((size_t)NND*HH*4);
  size_t o_tier2 = o;
  int*   flags=(int*)alloc((size_t)NND*4);
  float* gtab =(float*)alloc((size_t)NND*DD2*4);
  size_t o_tier3 = o;
  int tier = (ws_size >= o_tier3) ? 3 : ((ws_size >= o_tier2) ? 2 : ((ws_size >= o_rowbuf) ? 1 : 0));
  ull* tmp8 = (ull*)rowbuf;   // aliases rowbuf+h1base; build precedes their use

  keys_kernel<<<1,64,0,stream>>>(keys,bcnt);

  if(tier>=2){
    bcount_kernel<<<512,256,0,stream>>>(edge,bcnt);
    bscan_kernel<<<1,64,0,stream>>>(bcnt,boff,bcur,off);
    bscatter_kernel<<<512,256,0,stream>>>(edge,bcur,tmp8);
    bucket_csr_kernel<<<NBUK,256,0,stream>>>(boff,tmp8,off,inv,col);
  } else {
    hipMemsetAsync(cnt,0,(size_t)NND*4,stream);
    count_kernel<<<NE/256,256,0,stream>>>(edge,cnt);
    scan_kernel<<<1,1024,0,stream>>>(cnt,off,cur,inv);
    fill_kernel<<<NE/256,256,0,stream>>>(edge,cur,col);
  }
  sortseg_wave_kernel<<<NND/4,256,0,stream>>>(off,col);
  srcify_kernel<<<NE/256,256,0,stream>>>(col);

  const int GROWS2_GRID = BB*NROWS/16;           // 4352
  const int GDEDUP_GRID = (NND+15)/16;           // 6250
  const int MARK_GRID   = (BB*NROWS+255)/256;
  const int MASK_GRID   = (NND*HH+255)/256;

  if(tier==3){
    hipMemsetAsync(flags,0,(size_t)NND*4,stream);
    sage1base_kernel<<<NND/8,512,0,stream>>>(ent,off,col,inv,Wl1,bl1,Wr1,h1base);
    int gen=0;
    for(int r=0;r<2;++r){
      const int* pid = (r==0)? pos : g1b;
      int cidA=2*r, cidB=2*r+1;
      ++gen;
      mask_kernel<<<MASK_GRID,256,0,stream>>>(h1base,keys,cidA,h1);
      mark_kernel<<<MARK_GRID,256,0,stream>>>(users,pid,adj,flags,gen);
      grows_dedup_kernel<<<GDEDUP_GRID,512,0,stream>>>(h1,off,col,inv,Wl2,bl2,Wr2,keys,cidA,
                                                       flags,gen,gtab);
      sel1d_kernel<<<BB,64,0,stream>>>(gtab,users,pid,adj,ohb,l1b);
      ++gen;
      mask_kernel<<<MASK_GRID,256,0,stream>>>(h1base,keys,cidB,h1);
      mark_kernel<<<MARK_GRID,256,0,stream>>>(users,ohb,adj,flags,gen);
      grows_dedup_kernel<<<GDEDUP_GRID,512,0,stream>>>(h1,off,col,inv,Wl2,bl2,Wr2,keys,cidB,
                                                       flags,gen,gtab);
      sel2d_kernel<<<BB,64,0,stream>>>(gtab,keys,r,users,ohb,adj,du,di,train,neg,l1b,r,
                                       (r==0)?g1b:g2b,out);
    }
  } else if(tier==2){
    sage1base_kernel<<<NND/8,512,0,stream>>>(ent,off,col,inv,Wl1,bl1,Wr1,h1base);
    for(int r=0;r<2;++r){
      const int* pid = (r==0)? pos : g1b;
      int cidA=2*r, cidB=2*r+1;
      mask_kernel<<<MASK_GRID,256,0,stream>>>(h1base,keys,cidA,h1);
      grows2_kernel<<<GROWS2_GRID,512,0,stream>>>(h1,off,col,inv,Wl2,bl2,Wr2,keys,cidA,
                                                  users,pid,adj,rowbuf);
      sel1_kernel<<<BB,64,0,stream>>>(rowbuf,users,pid,adj,ohb,l1b);
      mask_kernel<<<MASK_GRID,256,0,stream>>>(h1base,keys,cidB,h1);
      grows2_kernel<<<GROWS2_GRID,512,0,stream>>>(h1,off,col,inv,Wl2,bl2,Wr2,keys,cidB,
                                                  users,ohb,adj,rowbuf);
      sel2_kernel<<<BB,64,0,stream>>>(rowbuf,keys,r,users,ohb,adj,du,di,train,neg,l1b,r,
                                      (r==0)?g1b:g2b,out);
    }
  } else if(tier==1){
    for(int r=0;r<2;++r){
      const int* pid = (r==0)? pos : g1b;
      int cidA=2*r, cidB=2*r+1;
      sage1_kernel<<<NND/4,256,0,stream>>>(ent,off,col,inv,Wl1,bl1,Wr1,keys,cidA,h1);
      grows2_kernel<<<GROWS2_GRID,512,0,stream>>>(h1,off,col,inv,Wl2,bl2,Wr2,keys,cidA,
                                                  users,pid,adj,rowbuf);
      sel1_kernel<<<BB,64,0,stream>>>(rowbuf,users,pid,adj,ohb,l1b);
      sage1_kernel<<<NND/4,256,0,stream>>>(ent,off,col,inv,Wl1,bl1,Wr1,keys,cidB,h1);
      grows2_kernel<<<GROWS2_GRID,512,0,stream>>>(h1,off,col,inv,Wl2,bl2,Wr2,keys,cidB,
                                                  users,ohb,adj,rowbuf);
      sel2_kernel<<<BB,64,0,stream>>>(rowbuf,keys,r,users,ohb,adj,du,di,train,neg,l1b,r,
                                      (r==0)?g1b:g2b,out);
    }
  } else {
    for(int r=0;r<2;++r){
      const int* pid = (r==0)? pos : g1b;
      int cidA=2*r, cidB=2*r+1;
      sage1_kernel<<<NND/4,256,0,stream>>>(ent,off,col,inv,Wl1,bl1,Wr1,keys,cidA,h1);
      fstep1_kernel<<<BB,256,0,stream>>>(h1,off,col,inv,Wl2,bl2,Wr2,keys,cidA,
                                         users,pid,adj,ohb,l1b);
      sage1_kernel<<<NND/4,256,0,stream>>>(ent,off,col,inv,Wl1,bl1,Wr1,keys,cidB,h1);
      fstep2_kernel<<<BB,256,0,stream>>>(h1,off,col,inv,Wl2,bl2,Wr2,keys,cidB,r,
                                         users,ohb,adj,du,di,train,neg,l1b,r,
                                         (r==0)?g1b:g2b,out);
    }
  }
}

// Round 21
// 865.562 us; speedup vs baseline: 1.0698x; 1.0698x over previous
//
#include <hip/hip_runtime.h>
#include <hip/hip_bf16.h>
#include <stdint.h>

#define NND 100000
#define KN 32
#define NE (NND*KN)
#define BB 2048
#define TT 50
#define DD0 64
#define HH 32
#define DD2 64
#define NROWS 34
#define BSH 9
#define NBUK ((NND + (1<<BSH) - 1) >> BSH)   // 196
#define PCHUNK 6250                           // NE / 512

typedef unsigned long long ull;

__device__ __forceinline__ void tf2x32(uint32_t k0, uint32_t k1, uint32_t& x0, uint32_t& x1){
  uint32_t k2 = k0 ^ k1 ^ 0x1BD11BDAu;
#define TFR(r) { x0 += x1; x1 = (x1<<(r)) | (x1>>(32-(r))); x1 ^= x0; }
  x0 += k0; x1 += k1;
  TFR(13) TFR(15) TFR(26) TFR(6)
  x0 += k1; x1 += k2 + 1u;
  TFR(17) TFR(29) TFR(16) TFR(24)
  x0 += k2; x1 += k0 + 2u;
  TFR(13) TFR(15) TFR(26) TFR(6)
  x0 += k0; x1 += k1 + 3u;
  TFR(17) TFR(29) TFR(16) TFR(24)
  x0 += k1; x1 += k2 + 4u;
  TFR(13) TFR(15) TFR(26) TFR(6)
  x0 += k2; x1 += k0 + 5u;
#undef TFR
}

__device__ __forceinline__ uint32_t xorbits(uint32_t ka, uint32_t kb, uint32_t i){
  uint32_t x0=0u, x1=i;
  tf2x32(ka,kb,x0,x1);
  return x0^x1;
}

__global__ void keys_kernel(uint32_t* keys, int* bcnt){
  int t=threadIdx.x;
  for(int i=t;i<NBUK+1;i+=64) bcnt[i]=0;
  if(t==0 && blockIdx.x==0){
    for(int cid=0;cid<4;++cid){
      uint32_t K0=0u,K1=(uint32_t)cid;
      tf2x32(0u,42u,K0,K1);
      uint32_t a0=0u,a1=0u; tf2x32(K0,K1,a0,a1);
      uint32_t b0=0u,b1=1u; tf2x32(K0,K1,b0,b1);
      keys[cid*4+0]=a0; keys[cid*4+1]=a1;
      keys[cid*4+2]=b0; keys[cid*4+3]=b1;
    }
    for(int r=0;r<2;++r){
      uint32_t F0=0u,F1=(uint32_t)(2*r);
      tf2x32(0u,7u,F0,F1);
      uint32_t a0=0u,a1=0u; tf2x32(F0,F1,a0,a1);
      uint32_t b0=0u,b1=1u; tf2x32(F0,F1,b0,b1);
      keys[16+r*4+0]=a0; keys[16+r*4+1]=a1;
      keys[16+r*4+2]=b0; keys[16+r*4+3]=b1;
    }
  }
}

// ===== bucketed CSR build =====
__global__ void __launch_bounds__(256) bcount_kernel(const int* __restrict__ edge, int* bcnt){
  __shared__ int h[NBUK];
  int t=threadIdx.x;
  for(int i=t;i<NBUK;i+=256) h[i]=0;
  __syncthreads();
  int start=blockIdx.x*PCHUNK, end=start+PCHUNK;
  for(int e=start+t;e<end;e+=256) atomicAdd(&h[edge[e]>>BSH],1);
  __syncthreads();
  for(int i=t;i<NBUK;i+=256) if(h[i]) atomicAdd(&bcnt[i],h[i]);
}

__global__ void bscan_kernel(const int* bcnt, int* boff, int* bcur, int* off){
  if(threadIdx.x==0 && blockIdx.x==0){
    int run=0;
    for(int i=0;i<NBUK;++i){ boff[i]=run; bcur[i]=run; run+=bcnt[i]; }
    boff[NBUK]=run;
    off[NND]=NE;
  }
}

__global__ void __launch_bounds__(256) bscatter_kernel(const int* __restrict__ edge,
    int* bcur, ull* __restrict__ tmp8){
  __shared__ int h[NBUK], base[NBUK], lcur[NBUK];
  int t=threadIdx.x;
  for(int i=t;i<NBUK;i+=256){ h[i]=0; lcur[i]=0; }
  __syncthreads();
  int start=blockIdx.x*PCHUNK, end=start+PCHUNK;
  for(int e=start+t;e<end;e+=256) atomicAdd(&h[edge[e]>>BSH],1);
  __syncthreads();
  for(int i=t;i<NBUK;i+=256) base[i] = h[i]? atomicAdd(&bcur[i],h[i]) : 0;
  __syncthreads();
  for(int e=start+t;e<end;e+=256){
    int d=edge[e];
    int b=d>>BSH;
    int r=atomicAdd(&lcur[b],1);
    tmp8[base[b]+r] = (((ull)(unsigned)d)<<32) | (unsigned)e;
  }
}

__global__ void __launch_bounds__(256) bucket_csr_kernel(const int* __restrict__ boff,
    const ull* __restrict__ tmp8, int* __restrict__ off, float* __restrict__ inv,
    int* __restrict__ col){
  __shared__ int cnt[512], pref[512], cur2[512];
  int b=blockIdx.x, t=threadIdx.x;
  int nb=b<<BSH;
  for(int i=t;i<512;i+=256) cnt[i]=0;
  __syncthreads();
  int lo=boff[b], hi=boff[b+1];
  for(int i=lo+t;i<hi;i+=256){
    int ld=(int)(tmp8[i]>>32)-nb;
    atomicAdd(&cnt[ld],1);
  }
  __syncthreads();
  if(t==0){ int run=lo; for(int i=0;i<512;++i){ pref[i]=run; cur2[i]=run; run+=cnt[i]; } }
  __syncthreads();
  for(int i=t;i<512;i+=256){
    int d=nb+i;
    if(d<NND){ off[d]=pref[i]; int c=cnt[i]; inv[d]=1.0f/(float)(c>0?c:1); }
  }
  __syncthreads();
  for(int i=lo+t;i<hi;i+=256){
    ull v=tmp8[i];
    int ld=(int)(v>>32)-nb;
    int r=atomicAdd(&cur2[ld],1);
    col[r]=(int)(v&0xffffffffu);
  }
}

// ===== fallback build =====
__global__ void count_kernel(const int* dst, int* cnt){
  int e = blockIdx.x*256 + threadIdx.x;
  if(e < NE) atomicAdd(&cnt[dst[e]], 1);
}
__global__ void scan_kernel(const int* cnt, int* off, int* cur, float* inv){
  __shared__ int part[1024];
  int t = threadIdx.x;
  const int CH = (NND + 1023)/1024;
  int lo = t*CH, hi = lo+CH; if(hi>NND) hi=NND;
  int s=0;
  for(int i=lo;i<hi;++i) s += cnt[i];
  part[t]=s;
  __syncthreads();
  if(t==0){ int run=0; for(int i=0;i<1024;++i){ int v=part[i]; part[i]=run; run+=v; } }
  __syncthreads();
  int run = part[t];
  for(int i=lo;i<hi;++i){
    off[i]=run; cur[i]=run;
    int c=cnt[i];
    inv[i]=1.0f/(float)(c>0?c:1);
    run+=c;
  }
  if(t==0) off[NND]=NE;
}
__global__ void fill_kernel(const int* dst, int* cur, int* col){
  int e = blockIdx.x*256 + threadIdx.x;
  if(e < NE){
    int d = dst[e];
    int slot = atomicAdd(&cur[d],1);
    col[slot] = e;
  }
}

// wave odd-even sort of each CSR segment
__global__ void __launch_bounds__(256) sortseg_wave_kernel(const int* off, int* col){
  int t=threadIdx.x, lane=t&63, w=t>>6;
  int node = blockIdx.x*4 + w;
  if(node>=NND) return;
  int lo=off[node], hi=off[node+1];
  int deg=hi-lo;
  if(deg<=1) return;
  if(deg<=64){
    int v = (lane<deg)? col[lo+lane] : 0x7fffffff;
    for(int p=0;p<64;++p){
      int partner;
      if((p&1)==0) partner = lane^1;
      else partner = (lane==0||lane==63)? lane : ((lane&1)? lane+1 : lane-1);
      int pv = __shfl(v, partner, 64);
      if(partner>lane) v = v<pv? v:pv;
      else if(partner<lane) v = v>pv? v:pv;
    }
    if(lane<deg) col[lo+lane]=v;
  } else if(lane==0){
    for(int i=lo+1;i<hi;++i){
      int v=col[i]; int j=i-1;
      while(j>=lo && col[j]>v){ col[j+1]=col[j]; --j; }
      col[j+1]=v;
    }
  }
}

// edge-id -> source-node (e>>5), post-sort
__global__ void srcify_kernel(int* col){
  int i = blockIdx.x*256 + threadIdx.x;
  if(i < NE) col[i] >>= 5;
}

// order-preserving 16-deep batched gather, 64-wide (col holds src node)
__device__ __forceinline__ float gather_seq(const float* __restrict__ src, int S, int d,
    const int* __restrict__ col, int lo, int hi, int lane){
  float acc=0.f;
  int deg=hi-lo, base=0;
  while(base<deg){
    int rem=deg-base; int cw = rem<64?rem:64;
    int cv = col[lo+base+ (lane<cw?lane:cw-1)];
    for(int k=0;k<cw;k+=16){
      int m=cw-k;
      float v[16];
#pragma unroll
      for(int j=0;j<16;++j){
        int q = (j<m)? k+j : k;
        int s = __shfl(cv,q,64);
        v[j] = src[(size_t)s*S+d];
      }
#pragma unroll
      for(int j=0;j<16;++j) if(j<m) acc += v[j];
    }
    base+=cw;
  }
  return acc;
}

// same, 32-wide (half-wave)
__device__ __forceinline__ float gather_seq32(const float* __restrict__ src, int S, int d,
    const int* __restrict__ col, int lo, int hi, int l){
  float acc=0.f;
  int deg=hi-lo, base=0;
  while(base<deg){
    int rem=deg-base; int cw = rem<32?rem:32;
    int cv = col[lo+base+ (l<cw?l:cw-1)];
    for(int k=0;k<cw;k+=16){
      int m=cw-k;
      float v[16];
#pragma unroll
      for(int j=0;j<16;++j){
        int q = (j<m)? k+j : k;
        int s = __shfl(cv,q,32);
        v[j] = src[(size_t)s*S+d];
      }
#pragma unroll
      for(int j=0;j<16;++j) if(j<m) acc += v[j];
    }
    base+=cw;
  }
  return acc;
}

// h1base = leaky_relu(agg@Wl1.T + bl1 + x@Wr1.T); 512 threads, 8 nodes/block
__global__ void __launch_bounds__(512) sage1base_kernel(const float* __restrict__ x,
    const int* __restrict__ off, const int* __restrict__ col,
    const float* __restrict__ inv, const float* __restrict__ Wl,
    const float* __restrict__ bl, const float* __restrict__ Wr,
    float* __restrict__ h1base){
  __shared__ float sWlT[DD0*HH], sWrT[DD0*HH];
  __shared__ float sA[8][DD0], sX[8][DD0];
  int t=threadIdx.x, lane=t&63, w=t>>6;
  for(int j=t;j<HH*DD0;j+=512){
    int k=j>>5, h=j&31;
    sWlT[j]=Wl[h*DD0+k]; sWrT[j]=Wr[h*DD0+k];
  }
  int node=blockIdx.x*8+w;
  int lo=off[node], hi=off[node+1];
  float acc=gather_seq(x,DD0,lane,col,lo,hi,lane);
  acc *= inv[node];
  sA[w][lane]=acc;
  sX[w][lane]=x[(size_t)node*DD0+lane];
  __syncthreads();
  if(lane<HH){
    float s1=0.f, s2=0.f;
    for(int k=0;k<DD0;++k){
      s1 += sA[w][k]*sWlT[k*HH+lane];
      s2 += sX[w][k]*sWrT[k*HH+lane];
    }
    float v=s1+bl[lane]+s2;
    v = (v>=0.f) ? v : 0.01f*v;
    h1base[(size_t)node*HH+lane]=v;
  }
}

__global__ void __launch_bounds__(256) mask_kernel(const float* __restrict__ h1base,
    const uint32_t* __restrict__ keys, int cid, float* __restrict__ h1){
  int j = blockIdx.x*256 + threadIdx.x;
  if(j < NND*HH){
    uint32_t bits = xorbits(keys[cid*4+0],keys[cid*4+1],(uint32_t)j);
    float v = h1base[j];
    h1[j] = ((bits>>31)==0u) ? 2.f*v : 0.f;
  }
}

// full sage1 (fallback tiers)
__global__ void __launch_bounds__(256) sage1_kernel(const float* __restrict__ x,
    const int* __restrict__ off, const int* __restrict__ col,
    const float* __restrict__ inv, const float* __restrict__ Wl,
    const float* __restrict__ bl, const float* __restrict__ Wr,
    const uint32_t* __restrict__ keys, int cid, float* __restrict__ h1o){
  __shared__ float sWlT[DD0*HH], sWrT[DD0*HH];
  __shared__ float sA[4][DD0], sX[4][DD0];
  int t=threadIdx.x, lane=t&63, w=t>>6;
  for(int j=t;j<HH*DD0;j+=256){
    int k=j>>5, h=j&31;
    sWlT[j]=Wl[h*DD0+k]; sWrT[j]=Wr[h*DD0+k];
  }
  int node=blockIdx.x*4+w;
  int lo=off[node], hi=off[node+1];
  float acc=gather_seq(x,DD0,lane,col,lo,hi,lane);
  acc *= inv[node];
  sA[w][lane]=acc;
  sX[w][lane]=x[(size_t)node*DD0+lane];
  __syncthreads();
  if(lane<HH){
    float s1=0.f, s2=0.f;
    for(int k=0;k<DD0;++k){
      s1 += sA[w][k]*sWlT[k*HH+lane];
      s2 += sX[w][k]*sWrT[k*HH+lane];
    }
    float v=s1+bl[lane]+s2;
    v = (v>=0.f) ? v : 0.01f*v;
    uint32_t j=(uint32_t)(node*HH+lane);
    uint32_t bits = xorbits(keys[cid*4+0],keys[cid*4+1],j);
    v = ((bits>>31)==0u) ? 2.f*v : 0.f;
    h1o[(size_t)node*HH+lane]=v;
  }
}

__device__ __forceinline__ float g_row_core(int n, int lane,
    const float* __restrict__ h1, const int* __restrict__ off,
    const int* __restrict__ col, const float* __restrict__ inv,
    const float* __restrict__ sWlT, const float* __restrict__ sWrT,
    const float* __restrict__ bl2, uint32_t k2a, uint32_t k2b){
  int lo=off[n], hi=off[n+1];
  int d=lane&31;
  float acc=gather_seq(h1,HH,d,col,lo,hi,lane);
  float aggd = acc*inv[n];
  float hd   = h1[(size_t)n*HH+d];
  float s1=0.f, s2=0.f;
  for(int k=0;k<HH;++k){
    float ak=__shfl(aggd,k,64);
    float hk=__shfl(hd,k,64);
    s1 += ak*sWlT[k*DD2+lane];
    s2 += hk*sWrT[k*DD2+lane];
  }
  float v=s1+bl2[lane]+s2;
  uint32_t j=(uint32_t)n*64u+(uint32_t)lane;
  uint32_t bits = xorbits(k2a,k2b,j);
  v = ((bits>>31)==0u) ? 2.f*v : 0.f;
  float ss=v*v;
  for(int m=1;m<64;m<<=1) ss += __shfl_xor(ss,m,64);
  return v/fmaxf(sqrtf(ss),1e-12f);
}

// half-wave g-row body (both output dims l, l+32)
__device__ __forceinline__ void g_row_half(int node, int l,
    const float* __restrict__ h1, const int* __restrict__ off,
    const int* __restrict__ col, const float* __restrict__ inv,
    const float* __restrict__ sWlT, const float* __restrict__ sWrT,
    const float* __restrict__ bl2, uint32_t k2a, uint32_t k2b,
    float* oa, float* ob){
  int lo=off[node], hi=off[node+1];
  float acc = gather_seq32(h1,HH,l,col,lo,hi,l);
  float aggd = acc*inv[node];
  float hd   = h1[(size_t)node*HH+l];
  float s1a=0.f,s2a=0.f,s1b=0.f,s2b=0.f;
  for(int k=0;k<HH;++k){
    float ak=__shfl(aggd,k,32);
    float hk=__shfl(hd,k,32);
    s1a += ak*sWlT[k*DD2+l];      s2a += hk*sWrT[k*DD2+l];
    s1b += ak*sWlT[k*DD2+l+32];   s2b += hk*sWrT[k*DD2+l+32];
  }
  float va=s1a+bl2[l]+s2a;
  float vb=s1b+bl2[l+32]+s2b;
  uint32_t ja=(uint32_t)node*64u+(uint32_t)l;
  va = ((xorbits(k2a,k2b,ja)>>31)==0u)     ? 2.f*va : 0.f;
  vb = ((xorbits(k2a,k2b,ja+32u)>>31)==0u) ? 2.f*vb : 0.f;
  float ssa=va*va, ssb=vb*vb;
  for(int m=1;m<32;m<<=1){ ssa += __shfl_xor(ssa,m,32); ssb += __shfl_xor(ssb,m,32); }
  float nr=fmaxf(sqrtf(ssa+ssb),1e-12f);
  *oa = va/nr; *ob = vb/nr;
}

// TWO g-rows per wave into rowbuf
__global__ void __launch_bounds__(512) grows2_kernel(
    const float* __restrict__ h1, const int* __restrict__ off,
    const int* __restrict__ col, const float* __restrict__ inv,
    const float* __restrict__ Wl2, const float* __restrict__ bl2,
    const float* __restrict__ Wr2, const uint32_t* __restrict__ keys, int cid,
    const int* __restrict__ users, const int* __restrict__ pid_arr,
    const int* __restrict__ adj, float* __restrict__ rowbuf){
  __shared__ float sWlT[HH*DD2], sWrT[HH*DD2];
  int t=threadIdx.x, lane=t&63, w=t>>6;
  int half=lane>>5, l=lane&31;
  for(int j=t;j<HH*DD2;j+=512){
    int k=j>>6, d=j&63;
    sWlT[j]=Wl2[d*HH+k]; sWrT[j]=Wr2[d*HH+k];
  }
  __syncthreads();
  int wg = blockIdx.x*16 + w*2 + half;
  int b = wg/NROWS, r = wg - b*NROWS;
  int pid = pid_arr[b];
  int node = (r==0)? users[b] : ((r==1)? pid : adj[(size_t)pid*KN + (r-2)]);
  float va,vb;
  g_row_half(node,l,h1,off,col,inv,sWlT,sWrT,bl2,keys[cid*4+2],keys[cid*4+3],&va,&vb);
  rowbuf[(size_t)wg*DD2 + l]      = va;
  rowbuf[(size_t)wg*DD2 + l + 32] = vb;
}

__global__ void __launch_bounds__(64) sel1_kernel(
    const float* __restrict__ rowbuf,
    const int* __restrict__ users, const int* __restrict__ pid_arr,
    const int* __restrict__ adj, int* __restrict__ oh_out, float* __restrict__ l1_out){
  int b=blockIdx.x, t=threadIdx.x;
  __shared__ float wsh[DD2];
  __shared__ float ps[KN];
  const float* rb = rowbuf + (size_t)b*NROWS*DD2;
  wsh[t] = rb[t]*rb[DD2+t];
  __syncthreads();
  if(t<KN){
    float p=0.f;
    const float* rr = rb + (size_t)(2+t)*DD2;
    for(int d=0;d<DD2;++d) p += rr[d]*wsh[d];
    ps[t]=p;
  }
  __syncthreads();
  if(t==0){
    float m=ps[0]; for(int k=1;k<KN;++k) m=fmaxf(m,ps[k]);
    float s=0.f;  for(int k=0;k<KN;++k) s += expf(ps[k]-m);
    int best=0; float bv=ps[0];
    for(int k=1;k<KN;++k) if(ps[k]>bv){bv=ps[k];best=k;}
    oh_out[b]=adj[(size_t)pid_arr[b]*KN+best];
    l1_out[b]=(ps[best]-m)-logf(s);
  }
}

__global__ void __launch_bounds__(64) sel2_kernel(
    const float* __restrict__ rowbuf, const uint32_t* __restrict__ keys, int kf_idx,
    const int* __restrict__ users, const int* __restrict__ oh,
    const int* __restrict__ adj,
    const float* __restrict__ du, const float* __restrict__ di,
    const int* __restrict__ train, const int* __restrict__ neg,
    const float* __restrict__ l1, int round,
    int* __restrict__ gneg_out, float* __restrict__ out){
  int b=blockIdx.x, t=threadIdx.x;
  __shared__ float wsh[DD2];
  __shared__ float ps[KN], lps[KN], rk[KN];
  __shared__ int nid[KN], cand[KN];
  __shared__ float msh[2];
  const float* rb = rowbuf + (size_t)b*NROWS*DD2;
  wsh[t] = rb[t]*rb[DD2+t];
  __syncthreads();
  if(t<KN){
    float p=0.f;
    const float* rr = rb + (size_t)(2+t)*DD2;
    for(int d=0;d<DD2;++d) p += rr[d]*wsh[d];
    ps[t]=p;
  }
  __syncthreads();
  if(t==0){
    float m=ps[0]; for(int k=1;k<KN;++k) m=fmaxf(m,ps[k]);
    float s=0.f;  for(int k=0;k<KN;++k) s += expf(ps[k]-m);
    msh[0]=m; msh[1]=logf(s);
    for(int k=0;k<KN;++k) nid[k]=k;
    for(int i=1;i<KN;++i){
      int v=nid[i]; float pv=ps[v]; int j=i-1;
      while(j>=0 && ps[nid[j]]>pv){ nid[j+1]=nid[j]; --j; }
      nid[j+1]=v;
    }
  }
  __syncthreads();
  if(t<KN){
    int n=t, c=adj[(size_t)oh[b]*KN + nid[n]];
    if(c<0 || c>49999){
      uint32_t i0=(uint32_t)(b*KN+n);
      const uint32_t* fk = keys + 16 + kf_idx*4;
      uint32_t hb = xorbits(fk[0], fk[1], i0);
      uint32_t lb = xorbits(fk[2], fk[3], i0);
      c=(int)(((hb%50000u)*17296u + (lb%50000u))%50000u);
    }
    cand[n]=c;
    lps[n]=(ps[nid[n]]-msh[0])-msh[1];
    int u=users[b];
    float rr=0.f;
    for(int d=0;d<DD2;++d) rr += du[(size_t)u*DD2+d]*di[(size_t)c*DD2+d];
    rk[n]=rr;
  }
  __syncthreads();
  if(t==0){
    int best=0; float bv=rk[0];
    for(int n=1;n<KN;++n) if(rk[n]>bv){bv=rk[n];best=n;}
    int gn=cand[best]; float lsel=lps[best];
    bool it=false;
    for(int t2=0;t2<TT;++t2) if(train[(size_t)b*TT+t2]==gn){it=true;break;}
    if(it) gn=neg[b];
    gneg_out[b]=gn;
    out[b*2+round]        = (float)gn;
    out[BB*2 + b*2+round] = l1[b]+lsel;
  }
}

// ===== fallback fused steps (tier 0) =====
__global__ void __launch_bounds__(256) fstep1_kernel(
    const float* __restrict__ h1, const int* __restrict__ off,
    const int* __restrict__ col, const float* __restrict__ inv,
    const float* __restrict__ Wl2, const float* __restrict__ bl2,
    const float* __restrict__ Wr2, const uint32_t* __restrict__ keys, int cid,
    const int* __restrict__ users, const int* __restrict__ pid_arr,
    const int* __restrict__ adj, int* __restrict__ oh_out, float* __restrict__ l1_out){
  __shared__ float sWlT[HH*DD2], sWrT[HH*DD2];
  __shared__ float rows[2+KN][DD2+1];
  __shared__ int nds[2+KN];
  __shared__ float ps[KN];
  int t=threadIdx.x, lane=t&63, w=t>>6, b=blockIdx.x;
  for(int j=t;j<HH*DD2;j+=256){
    int k=j>>6, d=j&63;
    sWlT[j]=Wl2[d*HH+k]; sWrT[j]=Wr2[d*HH+k];
  }
  if(t==0){ nds[0]=users[b]; nds[1]=pid_arr[b]; }
  if(t>=2 && t<2+KN) nds[t]=adj[(size_t)pid_arr[b]*KN + (t-2)];
  __syncthreads();
  uint32_t k2a=keys[cid*4+2], k2b=keys[cid*4+3];
  for(int r=w; r<2+KN; r+=4)
    rows[r][lane]=g_row_core(nds[r],lane,h1,off,col,inv,sWlT,sWrT,bl2,k2a,k2b);
  __syncthreads();
  if(t<KN){
    float p=0.f;
    for(int d=0;d<DD2;++d) p += rows[2+t][d]*(rows[0][d]*rows[1][d]);
    ps[t]=p;
  }
  __syncthreads();
  if(t==0){
    float m=ps[0]; for(int k=1;k<KN;++k) m=fmaxf(m,ps[k]);
    float s=0.f;  for(int k=0;k<KN;++k) s += expf(ps[k]-m);
    int best=0; float bv=ps[0];
    for(int k=1;k<KN;++k) if(ps[k]>bv){bv=ps[k];best=k;}
    oh_out[b]=nds[2+best];
    l1_out[b]=(ps[best]-m)-logf(s);
  }
}

__global__ void __launch_bounds__(256) fstep2_kernel(
    const float* __restrict__ h1, const int* __restrict__ off,
    const int* __restrict__ col, const float* __restrict__ inv,
    const float* __restrict__ Wl2, const float* __restrict__ bl2,
    const float* __restrict__ Wr2, const uint32_t* __restrict__ keys,
    int cid, int kf_idx,
    const int* __restrict__ users, const int* __restrict__ oh,
    const int* __restrict__ adj,
    const float* __restrict__ du, const float* __restrict__ di,
    const int* __restrict__ train, const int* __restrict__ neg,
    const float* __restrict__ l1, int round,
    int* __restrict__ gneg_out, float* __restrict__ out){
  __shared__ float sWlT[HH*DD2], sWrT[HH*DD2];
  __shared__ float rows[2+KN][DD2+1];
  __shared__ int nds[2+KN];
  __shared__ float ps[KN], lps[KN], rk[KN];
  __shared__ int nid[KN], cand[KN];
  __shared__ float msh[2];
  int t=threadIdx.x, lane=t&63, w=t>>6, b=blockIdx.x;
  for(int j=t;j<HH*DD2;j+=256){
    int k=j>>6, d=j&63;
    sWlT[j]=Wl2[d*HH+k]; sWrT[j]=Wr2[d*HH+k];
  }
  if(t==0){ nds[0]=users[b]; nds[1]=oh[b]; }
  if(t>=2 && t<2+KN) nds[t]=adj[(size_t)oh[b]*KN + (t-2)];
  __syncthreads();
  uint32_t k2a=keys[cid*4+2], k2b=keys[cid*4+3];
  for(int r=w; r<2+KN; r+=4)
    rows[r][lane]=g_row_core(nds[r],lane,h1,off,col,inv,sWlT,sWrT,bl2,k2a,k2b);
  __syncthreads();
  if(t<KN){
    float p=0.f;
    for(int d=0;d<DD2;++d) p += rows[2+t][d]*(rows[0][d]*rows[1][d]);
    ps[t]=p;
  }
  __syncthreads();
  if(t==0){
    float m=ps[0]; for(int k=1;k<KN;++k) m=fmaxf(m,ps[k]);
    float s=0.f;  for(int k=0;k<KN;++k) s += expf(ps[k]-m);
    msh[0]=m; msh[1]=logf(s);
    for(int k=0;k<KN;++k) nid[k]=k;
    for(int i=1;i<KN;++i){
      int v=nid[i]; float pv=ps[v]; int j=i-1;
      while(j>=0 && ps[nid[j]]>pv){ nid[j+1]=nid[j]; --j; }
      nid[j+1]=v;
    }
  }
  __syncthreads();
  if(t<KN){
    int n=t, c=nds[2+nid[n]];
    if(c<0 || c>49999){
      uint32_t i0=(uint32_t)(b*KN+n);
      const uint32_t* fk = keys + 16 + kf_idx*4;
      uint32_t hb = xorbits(fk[0], fk[1], i0);
      uint32_t lb = xorbits(fk[2], fk[3], i0);
      c=(int)(((hb%50000u)*17296u + (lb%50000u))%50000u);
    }
    cand[n]=c;
    lps[n]=(ps[nid[n]]-msh[0])-msh[1];
    int u=nds[0];
    float rr=0.f;
    for(int d=0;d<DD2;++d) rr += du[(size_t)u*DD2+d]*di[(size_t)c*DD2+d];
    rk[n]=rr;
  }
  __syncthreads();
  if(t==0){
    int best=0; float bv=rk[0];
    for(int n=1;n<KN;++n) if(rk[n]>bv){bv=rk[n];best=n;}
    int gn=cand[best]; float lsel=lps[best];
    bool it=false;
    for(int t2=0;t2<TT;++t2) if(train[(size_t)b*TT+t2]==gn){it=true;break;}
    if(it) gn=neg[b];
    gneg_out[b]=gn;
    out[b*2+round]        = (float)gn;
    out[BB*2 + b*2+round] = l1[b]+lsel;
  }
}

extern "C" void kernel_launch(void* const* d_in, const int* in_sizes, int n_in,
                              void* d_out, int out_size, void* d_ws, size_t ws_size,
                              hipStream_t stream) {
  const int*   users=(const int*)d_in[0];
  const int*   pos  =(const int*)d_in[1];
  const int*   neg  =(const int*)d_in[2];
  const int*   train=(const int*)d_in[3];
  const int*   adj  =(const int*)d_in[4];
  const int*   edge =(const int*)d_in[5];
  const float* ent  =(const float*)d_in[6];
  const float* Wl1  =(const float*)d_in[7];
  const float* bl1  =(const float*)d_in[8];
  const float* Wr1  =(const float*)d_in[9];
  const float* Wl2  =(const float*)d_in[10];
  const float* bl2  =(const float*)d_in[11];
  const float* Wr2  =(const float*)d_in[12];
  const float* du   =(const float*)d_in[13];
  const float* di   =(const float*)d_in[14];
  float* out=(float*)d_out;

  char* wsb=(char*)d_ws;
  size_t o=0;
  auto alloc=[&](size_t n)->char*{ char* p=wsb+o; o=(o+n+255)&~(size_t)255; return p; };
  uint32_t* keys=(uint32_t*)alloc(32*4);
  int*   bcnt=(int*)alloc((size_t)(NBUK+1)*4);
  int*   boff=(int*)alloc((size_t)(NBUK+1)*4);
  int*   bcur=(int*)alloc((size_t)NBUK*4);
  int*   ohb=(int*)alloc((size_t)BB*4);
  float* l1b=(float*)alloc((size_t)BB*4);
  int*   g1b=(int*)alloc((size_t)BB*4);
  int*   g2b=(int*)alloc((size_t)BB*4);
  int*   cnt=(int*)alloc((size_t)NND*4);
  int*   off=(int*)alloc((size_t)(NND+1)*4);
  int*   cur=(int*)alloc((size_t)NND*4);
  float* inv=(float*)alloc((size_t)NND*4);
  int*   col=(int*)alloc((size_t)NE*4);
  float* h1 =(float*)alloc((size_t)NND*HH*4);
  float* rowbuf=(float*)alloc((size_t)BB*NROWS*DD2*4);
  size_t o_rowbuf = o;
  float* h1base=(float*)alloc((size_t)NND*HH*4);
  size_t o_tier2 = o;
  int tier = (ws_size >= o_tier2) ? 2 : ((ws_size >= o_rowbuf) ? 1 : 0);
  ull* tmp8 = (ull*)rowbuf;   // aliases rowbuf+h1base; build precedes their use

  keys_kernel<<<1,64,0,stream>>>(keys,bcnt);

  if(tier>=2){
    bcount_kernel<<<512,256,0,stream>>>(edge,bcnt);
    bscan_kernel<<<1,64,0,stream>>>(bcnt,boff,bcur,off);
    bscatter_kernel<<<512,256,0,stream>>>(edge,bcur,tmp8);
    bucket_csr_kernel<<<NBUK,256,0,stream>>>(boff,tmp8,off,inv,col);
  } else {
    hipMemsetAsync(cnt,0,(size_t)NND*4,stream);
    count_kernel<<<NE/256,256,0,stream>>>(edge,cnt);
    scan_kernel<<<1,1024,0,stream>>>(cnt,off,cur,inv);
    fill_kernel<<<NE/256,256,0,stream>>>(edge,cur,col);
  }
  sortseg_wave_kernel<<<NND/4,256,0,stream>>>(off,col);
  srcify_kernel<<<NE/256,256,0,stream>>>(col);

  const int GROWS2_GRID = BB*NROWS/16;           // 4352
  const int MASK_GRID   = (NND*HH+255)/256;

  if(tier==2){
    sage1base_kernel<<<NND/8,512,0,stream>>>(ent,off,col,inv,Wl1,bl1,Wr1,h1base);
    for(int r=0;r<2;++r){
      const int* pid = (r==0)? pos : g1b;
      int cidA=2*r, cidB=2*r+1;
      mask_kernel<<<MASK_GRID,256,0,stream>>>(h1base,keys,cidA,h1);
      grows2_kernel<<<GROWS2_GRID,512,0,stream>>>(h1,off,col,inv,Wl2,bl2,Wr2,keys,cidA,
                                                  users,pid,adj,rowbuf);
      sel1_kernel<<<BB,64,0,stream>>>(rowbuf,users,pid,adj,ohb,l1b);
      mask_kernel<<<MASK_GRID,256,0,stream>>>(h1base,keys,cidB,h1);
      grows2_kernel<<<GROWS2_GRID,512,0,stream>>>(h1,off,col,inv,Wl2,bl2,Wr2,keys,cidB,
                                                  users,ohb,adj,rowbuf);
      sel2_kernel<<<BB,64,0,stream>>>(rowbuf,keys,r,users,ohb,adj,du,di,train,neg,l1b,r,
                                      (r==0)?g1b:g2b,out);
    }
  } else if(tier==1){
    for(int r=0;r<2;++r){
      const int* pid = (r==0)? pos : g1b;
      int cidA=2*r, cidB=2*r+1;
      sage1_kernel<<<NND/4,256,0,stream>>>(ent,off,col,inv,Wl1,bl1,Wr1,keys,cidA,h1);
      grows2_kernel<<<GROWS2_GRID,512,0,stream>>>(h1,off,col,inv,Wl2,bl2,Wr2,keys,cidA,
                                                  users,pid,adj,rowbuf);
      sel1_kernel<<<BB,64,0,stream>>>(rowbuf,users,pid,adj,ohb,l1b);
      sage1_kernel<<<NND/4,256,0,stream>>>(ent,off,col,inv,Wl1,bl1,Wr1,keys,cidB,h1);
      grows2_kernel<<<GROWS2_GRID,512,0,stream>>>(h1,off,col,inv,Wl2,bl2,Wr2,keys,cidB,
                                                  users,ohb,adj,rowbuf);
      sel2_kernel<<<BB,64,0,stream>>>(rowbuf,keys,r,users,ohb,adj,du,di,train,neg,l1b,r,
                                      (r==0)?g1b:g2b,out);
    }
  } else {
    for(int r=0;r<2;++r){
      const int* pid = (r==0)? pos : g1b;
      int cidA=2*r, cidB=2*r+1;
      sage1_kernel<<<NND/4,256,0,stream>>>(ent,off,col,inv,Wl1,bl1,Wr1,keys,cidA,h1);
      fstep1_kernel<<<BB,256,0,stream>>>(h1,off,col,inv,Wl2,bl2,Wr2,keys,cidA,
                                         users,pid,adj,ohb,l1b);
      sage1_kernel<<<NND/4,256,0,stream>>>(ent,off,col,inv,Wl1,bl1,Wr1,keys,cidB,h1);
      fstep2_kernel<<<BB,256,0,stream>>>(h1,off,col,inv,Wl2,bl2,Wr2,keys,cidB,r,
                                         users,ohb,adj,du,di,train,neg,l1b,r,
                                         (r==0)?g1b:g2b,out);
    }
  }
}